// Round 1
// baseline (209.363 us; speedup 1.0000x reference)
//
#include <hip/hip_runtime.h>
#include <hip/hip_bf16.h>
#include <math.h>

// Problem constants (fixed shapes from setup_inputs)
#define B_ 32
#define C_ 192
#define H_ 64
#define W_ 64
#define L_ 4096          // H_*W_
#define L4_ 1024         // L_/4
#define NTHREADS 256
#define PER_THREAD 16    // L_ / NTHREADS

// ---------------------------------------------------------------------------
// Kernel 1: per-batch stats + keep mask + stable compaction scan.
// One block per batch. Thread t owns tokens [t*16, t*16+16) (contiguous ->
// stable order is preserved by thread-ordered exclusive scan).
// ---------------------------------------------------------------------------
__global__ __launch_bounds__(NTHREADS) void stats_scan_kernel(
    const float* __restrict__ delta,  // [B, L]
    int*  __restrict__ src_idx,       // [B, L] out: src token for dest slot d
    int*  __restrict__ counts,        // [B]
    float* __restrict__ thetas)       // [B]
{
  const int b = blockIdx.x;
  const int t = threadIdx.x;
  const int lane = t & 63;
  const int wid  = t >> 6;            // 4 waves of 64

  __shared__ float  smin[4], smax[4];
  __shared__ float  s_lo, s_rng, s_theta;
  __shared__ double dsum[4], dsum2[4];
  __shared__ int    wsum[4];

  const float* dp = delta + (size_t)b * L_;

  // Load 16 contiguous floats (4 x float4 = one 64B line per thread)
  float a[PER_THREAD];
  const float4* d4 = (const float4*)dp;
  #pragma unroll
  for (int i = 0; i < 4; ++i) {
    float4 v = d4[t * 4 + i];
    a[i*4+0] = fabsf(v.x); a[i*4+1] = fabsf(v.y);
    a[i*4+2] = fabsf(v.z); a[i*4+3] = fabsf(v.w);
  }

  // ---- min/max reduce (f32, exact) ----
  float lmin = a[0], lmax = a[0];
  #pragma unroll
  for (int i = 1; i < PER_THREAD; ++i) {
    lmin = fminf(lmin, a[i]);
    lmax = fmaxf(lmax, a[i]);
  }
  #pragma unroll
  for (int off = 32; off; off >>= 1) {
    lmin = fminf(lmin, __shfl_down(lmin, off, 64));
    lmax = fmaxf(lmax, __shfl_down(lmax, off, 64));
  }
  if (lane == 0) { smin[wid] = lmin; smax[wid] = lmax; }
  __syncthreads();
  if (t == 0) {
    float lo = fminf(fminf(smin[0], smin[1]), fminf(smin[2], smin[3]));
    float hi = fmaxf(fmaxf(smax[0], smax[1]), fmaxf(smax[2], smax[3]));
    s_lo  = lo;
    s_rng = fmaxf(hi - lo, 1e-3f);   // clamp_min(0.001), f32 like reference
  }
  __syncthreads();
  const float lo  = s_lo;
  const float rng = s_rng;

  // ---- normalized importance (f32 elementwise, same rounding as ref),
  //      stats accumulated in double for a near-true theta ----
  double s = 0.0, s2 = 0.0;
  #pragma unroll
  for (int i = 0; i < PER_THREAD; ++i) {
    float imp = (a[i] - lo) / rng;   // f32 IEEE div, matches reference
    a[i] = imp;
    s  += (double)imp;
    s2 += (double)imp * (double)imp;
  }
  #pragma unroll
  for (int off = 32; off; off >>= 1) {
    s  += __shfl_down(s,  off, 64);
    s2 += __shfl_down(s2, off, 64);
  }
  if (lane == 0) { dsum[wid] = s; dsum2[wid] = s2; }
  __syncthreads();
  if (t == 0) {
    double S  = dsum[0]  + dsum[1]  + dsum[2]  + dsum[3];
    double S2 = dsum2[0] + dsum2[1] + dsum2[2] + dsum2[3];
    double mu  = S / (double)L_;
    double var = (S2 - S * S / (double)L_) / (double)(L_ - 1);  // ddof=1
    if (var < 0.0) var = 0.0;
    double sigma = sqrt(var);
    s_theta = (float)(mu - 0.1 * sigma);
  }
  __syncthreads();
  const float theta = s_theta;

  // ---- keep flags + exclusive scan over thread counts (stable order) ----
  int flags = 0, cnt = 0;
  #pragma unroll
  for (int i = 0; i < PER_THREAD; ++i) {
    int k = (a[i] >= theta) ? 1 : 0;
    cnt += k;
    flags |= (k << i);
  }
  // inclusive wave scan
  int inc = cnt;
  #pragma unroll
  for (int off = 1; off < 64; off <<= 1) {
    int y = __shfl_up(inc, off, 64);
    if (lane >= off) inc += y;
  }
  if (lane == 63) wsum[wid] = inc;
  __syncthreads();
  int base = inc - cnt;                       // exclusive within wave
  #pragma unroll
  for (int w = 0; w < 4; ++w)
    if (w < wid) base += wsum[w];             // add preceding waves

  int* sb = src_idx + (size_t)b * L_;
  int p = base;
  #pragma unroll
  for (int i = 0; i < PER_THREAD; ++i) {
    if ((flags >> i) & 1) { sb[p++] = t * PER_THREAD + i; }
  }
  if (t == NTHREADS - 1) {
    counts[b] = base + cnt;   // total kept
    thetas[b] = theta;
  }
}

// ---------------------------------------------------------------------------
// Kernel 2: the two scalar outputs (keep_ratio, theta_mean).
// ---------------------------------------------------------------------------
__global__ __launch_bounds__(64) void finalize_kernel(
    const int* __restrict__ counts, const float* __restrict__ thetas,
    float* __restrict__ out_tail)
{
  const int t = threadIdx.x;
  float c  = (t < B_) ? (float)counts[t] : 0.0f;
  float th = (t < B_) ? thetas[t]        : 0.0f;
  #pragma unroll
  for (int off = 32; off; off >>= 1) {
    c  += __shfl_down(c,  off, 64);
    th += __shfl_down(th, off, 64);
  }
  if (t == 0) {
    out_tail[0] = (c / (float)B_) / (float)L_;  // keep_ratio
    out_tail[1] = th / (float)B_;               // theta_mean
  }
}

// ---------------------------------------------------------------------------
// Kernel 3: gather. One thread per output float4 (4 dest tokens, fixed b,c).
// Coalesced float4 stores; gathered x reads (src monotone -> near-sequential);
// src entries beyond count are poison but never dereferenced (guard d < cnt).
// ---------------------------------------------------------------------------
__global__ __launch_bounds__(NTHREADS) void gather_kernel(
    const float* __restrict__ x,        // [B, C, L]
    const int*  __restrict__ src_idx,   // [B, L]
    const int*  __restrict__ counts,    // [B]
    float* __restrict__ out)            // [B, C, L]
{
  const int g  = blockIdx.x * NTHREADS + threadIdx.x;  // [0, B*C*L/4)
  const int j  = g & (L4_ - 1);   // float4 index within token dim
  const int bc = g >> 10;         // (b*C + c)
  const int b  = bc / C_;

  const int  cnt = counts[b];
  const int4 s4  = ((const int4*)(src_idx + (size_t)b * L_))[j];
  const float* xb = x + (size_t)bc * L_;
  const int d0 = j * 4;

  float4 r;
  r.x = (d0 + 0 < cnt) ? xb[s4.x] : 0.0f;
  r.y = (d0 + 1 < cnt) ? xb[s4.y] : 0.0f;
  r.z = (d0 + 2 < cnt) ? xb[s4.z] : 0.0f;
  r.w = (d0 + 3 < cnt) ? xb[s4.w] : 0.0f;
  ((float4*)out)[g] = r;
}

// ---------------------------------------------------------------------------
extern "C" void kernel_launch(void* const* d_in, const int* in_sizes, int n_in,
                              void* d_out, int out_size, void* d_ws, size_t ws_size,
                              hipStream_t stream) {
  const float* x     = (const float*)d_in[0];   // [32,192,64,64]
  const float* delta = (const float*)d_in[1];   // [32,1,64,64]
  float* out = (float*)d_out;                   // y (B*C*L) ++ keep_ratio ++ theta_mean

  // workspace layout
  int*   src_idx = (int*)d_ws;                                   // B*L ints = 512 KB
  int*   counts  = (int*)((char*)d_ws + (size_t)B_ * L_ * 4);    // 32 ints
  float* thetas  = (float*)((char*)d_ws + (size_t)B_ * L_ * 4 + 128);

  const size_t y_elems = (size_t)B_ * C_ * L_;  // 25,165,824

  stats_scan_kernel<<<B_, NTHREADS, 0, stream>>>(delta, src_idx, counts, thetas);
  finalize_kernel<<<1, 64, 0, stream>>>(counts, thetas, out + y_elems);
  gather_kernel<<<(int)(y_elems / 4 / NTHREADS), NTHREADS, 0, stream>>>(
      x, src_idx, counts, out);
}

// Round 3
// 184.081 us; speedup vs baseline: 1.1373x; 1.1373x over previous
//
#include <hip/hip_runtime.h>
#include <hip/hip_bf16.h>
#include <math.h>

// Problem constants (fixed shapes from setup_inputs)
#define B_ 32
#define C_ 192
#define H_ 64
#define W_ 64
#define L_ 4096          // H_*W_
#define L4_ 1024         // L_/4
#define NTHREADS 256
#define PER_THREAD 16    // L_ / NTHREADS

typedef float  f32x4 __attribute__((ext_vector_type(4)));  // clang-native vec4

// ---------------------------------------------------------------------------
// Kernel 1: per-batch stats + keep mask + stable compaction scan.
// One block per batch. Thread t owns tokens [t*16, t*16+16) (contiguous ->
// stable order is preserved by thread-ordered exclusive scan).
// ---------------------------------------------------------------------------
__global__ __launch_bounds__(NTHREADS) void stats_scan_kernel(
    const float* __restrict__ delta,  // [B, L]
    int*  __restrict__ src_idx,       // [B, L] out: src token for dest slot d
    int*  __restrict__ counts,        // [B]
    float* __restrict__ thetas)       // [B]
{
  const int b = blockIdx.x;
  const int t = threadIdx.x;
  const int lane = t & 63;
  const int wid  = t >> 6;            // 4 waves of 64

  __shared__ float  smin[4], smax[4];
  __shared__ float  s_lo, s_rng, s_theta;
  __shared__ double dsum[4], dsum2[4];
  __shared__ int    wsum[4];

  const float* dp = delta + (size_t)b * L_;

  // Load 16 contiguous floats (4 x float4 = one 64B line per thread)
  float a[PER_THREAD];
  const float4* d4 = (const float4*)dp;
  #pragma unroll
  for (int i = 0; i < 4; ++i) {
    float4 v = d4[t * 4 + i];
    a[i*4+0] = fabsf(v.x); a[i*4+1] = fabsf(v.y);
    a[i*4+2] = fabsf(v.z); a[i*4+3] = fabsf(v.w);
  }

  // ---- min/max reduce (f32, exact) ----
  float lmin = a[0], lmax = a[0];
  #pragma unroll
  for (int i = 1; i < PER_THREAD; ++i) {
    lmin = fminf(lmin, a[i]);
    lmax = fmaxf(lmax, a[i]);
  }
  #pragma unroll
  for (int off = 32; off; off >>= 1) {
    lmin = fminf(lmin, __shfl_down(lmin, off, 64));
    lmax = fmaxf(lmax, __shfl_down(lmax, off, 64));
  }
  if (lane == 0) { smin[wid] = lmin; smax[wid] = lmax; }
  __syncthreads();
  if (t == 0) {
    float lo = fminf(fminf(smin[0], smin[1]), fminf(smin[2], smin[3]));
    float hi = fmaxf(fmaxf(smax[0], smax[1]), fmaxf(smax[2], smax[3]));
    s_lo  = lo;
    s_rng = fmaxf(hi - lo, 1e-3f);   // clamp_min(0.001), f32 like reference
  }
  __syncthreads();
  const float lo  = s_lo;
  const float rng = s_rng;

  // ---- normalized importance (f32 elementwise, same rounding as ref),
  //      stats accumulated in double for a near-true theta ----
  double s = 0.0, s2 = 0.0;
  #pragma unroll
  for (int i = 0; i < PER_THREAD; ++i) {
    float imp = (a[i] - lo) / rng;   // f32 IEEE div, matches reference
    a[i] = imp;
    s  += (double)imp;
    s2 += (double)imp * (double)imp;
  }
  #pragma unroll
  for (int off = 32; off; off >>= 1) {
    s  += __shfl_down(s,  off, 64);
    s2 += __shfl_down(s2, off, 64);
  }
  if (lane == 0) { dsum[wid] = s; dsum2[wid] = s2; }
  __syncthreads();
  if (t == 0) {
    double S  = dsum[0]  + dsum[1]  + dsum[2]  + dsum[3];
    double S2 = dsum2[0] + dsum2[1] + dsum2[2] + dsum2[3];
    double mu  = S / (double)L_;
    double var = (S2 - S * S / (double)L_) / (double)(L_ - 1);  // ddof=1
    if (var < 0.0) var = 0.0;
    double sigma = sqrt(var);
    s_theta = (float)(mu - 0.1 * sigma);
  }
  __syncthreads();
  const float theta = s_theta;

  // ---- keep flags + exclusive scan over thread counts (stable order) ----
  int flags = 0, cnt = 0;
  #pragma unroll
  for (int i = 0; i < PER_THREAD; ++i) {
    int k = (a[i] >= theta) ? 1 : 0;
    cnt += k;
    flags |= (k << i);
  }
  // inclusive wave scan
  int inc = cnt;
  #pragma unroll
  for (int off = 1; off < 64; off <<= 1) {
    int y = __shfl_up(inc, off, 64);
    if (lane >= off) inc += y;
  }
  if (lane == 63) wsum[wid] = inc;
  __syncthreads();
  int base = inc - cnt;                       // exclusive within wave
  #pragma unroll
  for (int w = 0; w < 4; ++w)
    if (w < wid) base += wsum[w];             // add preceding waves

  int* sb = src_idx + (size_t)b * L_;
  int p = base;
  #pragma unroll
  for (int i = 0; i < PER_THREAD; ++i) {
    if ((flags >> i) & 1) { sb[p++] = t * PER_THREAD + i; }
  }
  if (t == NTHREADS - 1) {
    counts[b] = base + cnt;   // total kept
    thetas[b] = theta;
  }
}

// ---------------------------------------------------------------------------
// Kernel 2: the two scalar outputs (keep_ratio, theta_mean).
// ---------------------------------------------------------------------------
__global__ __launch_bounds__(64) void finalize_kernel(
    const int* __restrict__ counts, const float* __restrict__ thetas,
    float* __restrict__ out_tail)
{
  const int t = threadIdx.x;
  float c  = (t < B_) ? (float)counts[t] : 0.0f;
  float th = (t < B_) ? thetas[t]        : 0.0f;
  #pragma unroll
  for (int off = 32; off; off >>= 1) {
    c  += __shfl_down(c,  off, 64);
    th += __shfl_down(th, off, 64);
  }
  if (t == 0) {
    out_tail[0] = (c / (float)B_) / (float)L_;  // keep_ratio
    out_tail[1] = th / (float)B_;               // theta_mean
  }
}

// ---------------------------------------------------------------------------
// Kernel 3: row compaction via LDS. One block per (b,c) row.
// Phase 1: stream the 4096-float row into LDS with coalesced float4 loads.
// Phase 2: permute in LDS (dword gather, <=2-way conflicts ~ free), store
//          coalesced float4 with nontemporal hint (write stream is never
//          re-read; keep it out of L2 so src_idx/x lines stay resident).
// ---------------------------------------------------------------------------
__global__ __launch_bounds__(NTHREADS) void gather_kernel(
    const float* __restrict__ x,        // [B, C, L]
    const int*  __restrict__ src_idx,   // [B, L]
    const int*  __restrict__ counts,    // [B]
    float* __restrict__ out)            // [B, C, L]
{
  __shared__ float row[L_];             // 16 KB

  const int bc = blockIdx.x;            // [0, B*C)
  const int b  = bc / C_;
  const int t  = threadIdx.x;

  const float4* x4 = (const float4*)(x + (size_t)bc * L_);
  float4* r4 = (float4*)row;

  // Phase 1: coalesced row load -> LDS
  #pragma unroll
  for (int i = 0; i < 4; ++i) {
    r4[t + NTHREADS * i] = x4[t + NTHREADS * i];
  }
  __syncthreads();

  // Phase 2: LDS gather -> coalesced nontemporal store
  const int  cnt = counts[b];
  const int4* s4b = (const int4*)(src_idx + (size_t)b * L_);
  f32x4* o4 = (f32x4*)(out + (size_t)bc * L_);

  #pragma unroll
  for (int i = 0; i < 4; ++i) {
    const int j  = t + NTHREADS * i;    // float4 index in [0, 1024)
    const int d0 = j * 4;
    const int4 s = s4b[j];              // L2-resident after first channel
    f32x4 r;
    r.x = (d0 + 0 < cnt) ? row[s.x] : 0.0f;
    r.y = (d0 + 1 < cnt) ? row[s.y] : 0.0f;
    r.z = (d0 + 2 < cnt) ? row[s.z] : 0.0f;
    r.w = (d0 + 3 < cnt) ? row[s.w] : 0.0f;
    __builtin_nontemporal_store(r, o4 + j);
  }
}

// ---------------------------------------------------------------------------
extern "C" void kernel_launch(void* const* d_in, const int* in_sizes, int n_in,
                              void* d_out, int out_size, void* d_ws, size_t ws_size,
                              hipStream_t stream) {
  const float* x     = (const float*)d_in[0];   // [32,192,64,64]
  const float* delta = (const float*)d_in[1];   // [32,1,64,64]
  float* out = (float*)d_out;                   // y (B*C*L) ++ keep_ratio ++ theta_mean

  // workspace layout
  int*   src_idx = (int*)d_ws;                                   // B*L ints = 512 KB
  int*   counts  = (int*)((char*)d_ws + (size_t)B_ * L_ * 4);    // 32 ints
  float* thetas  = (float*)((char*)d_ws + (size_t)B_ * L_ * 4 + 128);

  const size_t y_elems = (size_t)B_ * C_ * L_;  // 25,165,824

  stats_scan_kernel<<<B_, NTHREADS, 0, stream>>>(delta, src_idx, counts, thetas);
  finalize_kernel<<<1, 64, 0, stream>>>(counts, thetas, out + y_elems);
  gather_kernel<<<B_ * C_, NTHREADS, 0, stream>>>(x, src_idx, counts, out);
}